// Round 2
// baseline (88747.034 us; speedup 1.0000x reference)
//
#include <hip/hip_runtime.h>
#include <math.h>

#define DT 0.01f
constexpr int T = 512, B = 128, I = 256, H = 1024, O = 256;
constexpr int WGS = 256;       // 1 per CU (LDS-forced) -> co-resident by capacity
constexpr int THREADS = 1024;  // 16 waves

// ---- workspace layout (float offsets) ----
constexpr size_t OFF_HU0  = 0;
constexpr size_t OFF_HU1  = OFF_HU0 + (size_t)B * H;
constexpr size_t OFF_OSUM = OFF_HU1 + (size_t)B * H;
constexpr size_t OFF_SYNC = OFF_OSUM + (size_t)B * H;   // 16 ints

// ---- LDS layout (bytes): weights in MFMA-fragment order, hi/lo bf16 ----
constexpr int SM_WO_HI = 0;                              // 32 ks * 64 lanes * 8 bf16
constexpr int SM_WO_LO = SM_WO_HI + 32 * 512 * 2;        // 32768
constexpr int SM_WH_HI = SM_WO_LO + 32 * 512 * 2;        // 65536
constexpr int SM_WH_LO = SM_WH_HI + 40 * 512 * 2;        // 106496
constexpr int SM_RED   = SM_WH_LO + 40 * 512 * 2;        // 147456
constexpr int RED_STRIDE = 18;                           // 4*18 % 32 == 8 -> 2-way max
constexpr int SM_HU    = SM_RED + 2 * 32 * RED_STRIDE * 4; // 152064
constexpr int SM_HV    = SM_HU + 2048;
constexpr int SM_OU    = SM_HV + 2048;
constexpr int SM_OSUM  = SM_OU + 2048;
constexpr int SM_COEF  = SM_OSUM + 2048;
constexpr int SM_BYTES = SM_COEF + 5 * 16 * 4;           // 160576 <= 163840

typedef __attribute__((ext_vector_type(8))) short short8v;
typedef __attribute__((ext_vector_type(4))) float f32x4;

static __device__ inline short f2bf(float f) {           // RTN-even fp32->bf16
    unsigned u = __builtin_bit_cast(unsigned, f);
    u += 0x7fffu + ((u >> 16) & 1u);
    return (short)(u >> 16);
}
static __device__ inline float bf2f(short s) {
    return __builtin_bit_cast(float, ((unsigned)(unsigned short)s) << 16);
}

// Two-level grid barrier: 8 groups of 32 WGs -> root. Device-scope atomics.
static __device__ inline void gridbar(int* sync, int gen) {
    __threadfence();
    __syncthreads();
    if (threadIdx.x == 0) {
        int g = (int)(blockIdx.x >> 5);
        int p = __hip_atomic_fetch_add(&sync[8 + g], 1, __ATOMIC_ACQ_REL, __HIP_MEMORY_SCOPE_AGENT);
        bool released = false;
        if (p == 31) {
            int q = __hip_atomic_fetch_add(&sync[1], 1, __ATOMIC_ACQ_REL, __HIP_MEMORY_SCOPE_AGENT);
            if (q == 7) {
                #pragma unroll
                for (int i = 0; i < 8; ++i)
                    __hip_atomic_store(&sync[8 + i], 0, __ATOMIC_RELAXED, __HIP_MEMORY_SCOPE_AGENT);
                __hip_atomic_store(&sync[1], 0, __ATOMIC_RELAXED, __HIP_MEMORY_SCOPE_AGENT);
                __hip_atomic_fetch_add(&sync[0], 1, __ATOMIC_RELEASE, __HIP_MEMORY_SCOPE_AGENT);
                released = true;
            }
        }
        if (!released) {
            while (__hip_atomic_load(&sync[0], __ATOMIC_ACQUIRE, __HIP_MEMORY_SCOPE_AGENT) <= gen)
                __builtin_amdgcn_s_sleep(2);
        }
    }
    __syncthreads();
    __threadfence();
}

__global__ void init_sync(int* sync) {
    if (threadIdx.x < 16) sync[threadIdx.x] = 0;
}

// Persistent RNN kernel. Per WG: output tile 32 rows x 16 cols.
// 16 waves: gemm = wid&1 (0: p=hu@W_o^T, 1: in_sum=[x,hu]@W_h^T),
// mtile = (wid>>1)&1, kslice = wid>>2 (4-way K split, reduced via LDS atomics).
// Each K-step: 3 MFMAs (ah*bh + al*bh + ah*bl) = bf16 hi/lo fp32-emulation.
__global__ __launch_bounds__(THREADS)
void rnn_persist(const float* __restrict__ x, const float* __restrict__ W_h,
                 const float* __restrict__ W_o,
                 const float* __restrict__ omega, const float* __restrict__ b_offset,
                 const float* __restrict__ tau_mem, const float* __restrict__ gain,
                 float* __restrict__ hu0, float* __restrict__ hu1,
                 float* __restrict__ osum_g, int* __restrict__ sync) {
    extern __shared__ char sm[];
    short* WOH = (short*)(sm + SM_WO_HI);
    short* WOL = (short*)(sm + SM_WO_LO);
    short* WHH = (short*)(sm + SM_WH_HI);
    short* WHL = (short*)(sm + SM_WH_LO);
    float* red  = (float*)(sm + SM_RED);
    float* shu  = (float*)(sm + SM_HU);
    float* shv  = (float*)(sm + SM_HV);
    float* sou  = (float*)(sm + SM_OU);
    float* sosum= (float*)(sm + SM_OSUM);
    float* coef = (float*)(sm + SM_COEF);

    const int tid = threadIdx.x;
    const int wg  = blockIdx.x;
    // XCD swizzle: col-groups 8x..8x+7 pinned per XCD
    const int xcd = wg & 7, idx = wg >> 3;
    const int cg  = xcd * 8 + (idx >> 2);
    const int rt  = idx & 3;
    const int row0 = rt * 32, col0 = cg * 16;

    // ---- one-time: stage weights into LDS in fragment order (hi/lo bf16) ----
    for (int i = tid; i < 32 * 512; i += THREADS) {
        int ks = i >> 9, lane = (i >> 3) & 63, j = i & 7;
        int col = col0 + (lane & 15);
        int k = ks * 32 + ((lane >> 4) << 3) + j;
        float v = W_o[(size_t)col * H + k];
        short h = f2bf(v);
        WOH[i] = h;
        WOL[i] = f2bf(v - bf2f(h));
    }
    for (int i = tid; i < 40 * 512; i += THREADS) {
        int ks = i >> 9, lane = (i >> 3) & 63, j = i & 7;
        int col = col0 + (lane & 15);
        int k = ks * 32 + ((lane >> 4) << 3) + j;
        float v = W_h[(size_t)col * (I + H) + k];
        short h = f2bf(v);
        WHH[i] = h;
        WHL[i] = f2bf(v - bf2f(h));
    }
    if (tid < 16) {
        int col = col0 + tid;
        float om = fabsf(omega[col]);
        float om2 = om * om;
        float bb = om2 * 0.005f + fabsf(b_offset[col]);
        float al = expf(-1.0f / fabsf(tau_mem[col]));
        float g  = gain[col];
        coef[tid]      = g * (1.0f - 2.0f * bb * DT);  // k1
        coef[16 + tid] = g * DT;                       // k2
        coef[32 + tid] = g * om2 * DT;                 // k3
        coef[48 + tid] = al;                           // alpha
        coef[64 + tid] = 1.0f - al;
    }
    for (int i = tid; i < 512; i += THREADS) { shu[i] = 0; shv[i] = 0; sou[i] = 0; sosum[i] = 0; }
    for (int i = tid; i < 512; i += THREADS) hu0[(size_t)wg * 512 + i] = 0.0f;

    int bars = 0;
    gridbar(sync, bars++);

    const int wid = tid >> 6, lane = tid & 63;
    const int gemm = wid & 1, mtile = (wid >> 1) & 1, kslice = wid >> 2;
    const int rowg = row0 + mtile * 16 + (lane & 15);
    const int koff = (lane >> 4) << 3;
    const short8v* BH = (const short8v*)(gemm ? (sm + SM_WH_HI) : (sm + SM_WO_HI));
    const short8v* BL = (const short8v*)(gemm ? (sm + SM_WH_LO) : (sm + SM_WO_LO));
    const int NK = gemm ? 40 : 32;
    const int ks0 = (NK * kslice) >> 2, ks1 = (NK * (kslice + 1)) >> 2;

    float* hub[2] = {hu0, hu1};

    for (int s = 0; s <= T; ++s) {
        const bool fin = (s == T);
        const float* hu_cur = hub[s & 1];
        float* hu_nxt = hub[(s + 1) & 1];
        const float* xs = x + (size_t)s * B * I;

        for (int i = tid; i < 2 * 32 * RED_STRIDE; i += THREADS) red[i] = 0.0f;
        __syncthreads();

        if (!fin || gemm == 0) {
            f32x4 acc = {0, 0, 0, 0};
            const float* hurow = hu_cur + (size_t)rowg * H + koff;
            const float* xrow  = xs + (size_t)rowg * I + koff;
            for (int ks = ks0; ks < ks1; ++ks) {
                const float* ap = gemm ? ((ks < 8) ? xrow + ks * 32 : hurow + ks * 32 - 256)
                                       : hurow + ks * 32;
                float4 a0 = *(const float4*)ap;
                float4 a1 = *(const float4*)(ap + 4);
                float av[8] = {a0.x, a0.y, a0.z, a0.w, a1.x, a1.y, a1.z, a1.w};
                short8v ah, al;
                #pragma unroll
                for (int j = 0; j < 8; ++j) {
                    short h = f2bf(av[j]);
                    ah[j] = h;
                    al[j] = f2bf(av[j] - bf2f(h));
                }
                short8v bh = BH[ks * 64 + lane];
                short8v bl = BL[ks * 64 + lane];
                acc = __builtin_amdgcn_mfma_f32_16x16x32_bf16(ah, bh, acc, 0, 0, 0);
                acc = __builtin_amdgcn_mfma_f32_16x16x32_bf16(al, bh, acc, 0, 0, 0);
                acc = __builtin_amdgcn_mfma_f32_16x16x32_bf16(ah, bl, acc, 0, 0, 0);
            }
            float* rbase = red + gemm * 32 * RED_STRIDE;
            #pragma unroll
            for (int r = 0; r < 4; ++r) {
                int crow = mtile * 16 + ((lane >> 4) << 2) + r;  // C/D: col=lane&15, row=(lane>>4)*4+r
                atomicAdd(&rbase[crow * RED_STRIDE + (lane & 15)], acc[r]);
            }
        }
        __syncthreads();

        if (tid < 512) {
            int r = tid >> 4, cc = tid & 15;
            float p   = red[r * RED_STRIDE + cc];
            float al  = coef[48 + cc], alm = coef[64 + cc];
            float oun = sou[tid] * al + p * alm;
            sou[tid] = oun;
            sosum[tid] += oun;
            if (!fin) {
                float si  = red[32 * RED_STRIDE + r * RED_STRIDE + cc];
                float huo = shu[tid];
                float hvn = shv[tid] + huo * DT;
                float hun = coef[cc] * huo + coef[16 + cc] * si - coef[32 + cc] * hvn;
                shv[tid] = hvn;
                shu[tid] = hun;
                hu_nxt[(size_t)(row0 + r) * H + col0 + cc] = hun;
            } else {
                osum_g[(size_t)(row0 + r) * H + col0 + cc] = sosum[tid];
            }
        }
        if (!fin) gridbar(sync, bars++);
    }
}

// acc = ou_sum @ W_out^T + T*b_out  (fp32, tiny: 67 MFLOP)
constexpr int KC = 128, BT = 32, CT = 16;
__global__ __launch_bounds__(256)
void readout_kernel(const float* __restrict__ ou_sum, const float* __restrict__ W_out,
                    const float* __restrict__ b_out, float* __restrict__ out) {
    __shared__ float act[BT][KC + 4];
    __shared__ float w[CT][KC + 4];
    int wg = blockIdx.x;
    int bt = wg & 3, cg = wg >> 2;
    int row0 = bt * BT, col0 = cg * CT;
    int tid = threadIdx.x;
    int c = tid & 15, rr = tid >> 4;

    float4 acc0 = {0, 0, 0, 0}, acc1 = {0, 0, 0, 0};
    for (int kc = 0; kc < H / KC; ++kc) {
        int k0 = kc * KC;
        for (int i = tid; i < BT * (KC / 4); i += 256) {
            int r = i >> 5, c4 = (i & 31) * 4;
            *(float4*)&act[r][c4] = *(const float4*)&ou_sum[(size_t)(row0 + r) * H + k0 + c4];
        }
        for (int i = tid; i < CT * (KC / 4); i += 256) {
            int r = i >> 5, c4 = (i & 31) * 4;
            *(float4*)&w[r][c4] = *(const float4*)&W_out[(size_t)(col0 + r) * H + k0 + c4];
        }
        __syncthreads();
        #pragma unroll
        for (int k4 = 0; k4 < KC / 4; ++k4) {
            float4 a0 = *(const float4*)&act[rr][k4 * 4];
            float4 a1 = *(const float4*)&act[rr + 16][k4 * 4];
            float4 w0 = *(const float4*)&w[c][k4 * 4];
            acc0.x = fmaf(a0.x, w0.x, acc0.x); acc0.y = fmaf(a0.y, w0.y, acc0.y);
            acc0.z = fmaf(a0.z, w0.z, acc0.z); acc0.w = fmaf(a0.w, w0.w, acc0.w);
            acc1.x = fmaf(a1.x, w0.x, acc1.x); acc1.y = fmaf(a1.y, w0.y, acc1.y);
            acc1.z = fmaf(a1.z, w0.z, acc1.z); acc1.w = fmaf(a1.w, w0.w, acc1.w);
        }
        __syncthreads();
    }
    float v0 = (acc0.x + acc0.y) + (acc0.z + acc0.w);
    float v1 = (acc1.x + acc1.y) + (acc1.z + acc1.w);
    int gcol = col0 + c;
    float bo = b_out[gcol] * (float)T;
    out[(size_t)(row0 + rr) * O + gcol] = v0 + bo;
    out[(size_t)(row0 + rr + 16) * O + gcol] = v1 + bo;
}

extern "C" void kernel_launch(void* const* d_in, const int* in_sizes, int n_in,
                              void* d_out, int out_size, void* d_ws, size_t ws_size,
                              hipStream_t stream) {
    const float* x        = (const float*)d_in[0];
    const float* W_h      = (const float*)d_in[1];
    const float* gain     = (const float*)d_in[2];
    const float* omega    = (const float*)d_in[3];
    const float* b_offset = (const float*)d_in[4];
    const float* W_o      = (const float*)d_in[5];
    const float* tau_mem  = (const float*)d_in[6];
    const float* W_out    = (const float*)d_in[7];
    const float* b_out    = (const float*)d_in[8];
    float* ws  = (float*)d_ws;
    float* out = (float*)d_out;
    int* sync  = (int*)(ws + OFF_SYNC);

    init_sync<<<1, 64, 0, stream>>>(sync);
    rnn_persist<<<WGS, THREADS, SM_BYTES, stream>>>(
        x, W_h, W_o, omega, b_offset, tau_mem, gain,
        ws + OFF_HU0, ws + OFF_HU1, ws + OFF_OSUM, sync);
    readout_kernel<<<64, 256, 0, stream>>>(ws + OFF_OSUM, W_out, b_out, out);
}

// Round 4
// 5346.148 us; speedup vs baseline: 16.6002x; 16.6002x over previous
//
#include <hip/hip_runtime.h>
#include <math.h>

#define DT 0.01f
constexpr int T = 512, B = 128, I = 256, H = 1024, O = 256;
constexpr int K = I + H;          // 1280
constexpr int NKS_H = K / 32;     // 40 (W_h k-steps; 0..7 = x part, 8..39 = hu part)
constexpr int NKS_O = H / 32;     // 32 (W_o k-steps)

// ---- workspace layout (float offsets) ----
constexpr size_t OFF_HUF0 = 0;                               // hu fp32 ping
constexpr size_t OFF_HUF1 = OFF_HUF0 + (size_t)B * H;        // hu fp32 pong
constexpr size_t OFF_HV   = OFF_HUF1 + (size_t)B * H;
constexpr size_t OFF_OU   = OFF_HV   + (size_t)B * H;
constexpr size_t OFF_OSUM = OFF_OU   + (size_t)B * H;
constexpr size_t OFF_HUH0 = OFF_OSUM + (size_t)B * H;        // hu hi bf16 (shorts), B*H/2 floats
constexpr size_t OFF_HUL0 = OFF_HUH0 + (size_t)B * H / 2;
constexpr size_t OFF_HUH1 = OFF_HUL0 + (size_t)B * H / 2;
constexpr size_t OFF_HUL1 = OFF_HUH1 + (size_t)B * H / 2;
constexpr size_t ZERO_END = OFF_HUL1 + (size_t)B * H / 2;    // 917504
constexpr size_t OFF_COEF = ZERO_END;                        // k1,k2,k3,alpha,1-alpha (5*H)
constexpr size_t OFF_WHH  = OFF_COEF + 5 * (size_t)H;        // 64*40*64*8 shorts
constexpr size_t OFF_WHL  = OFF_WHH + 64 * 40 * 64 * 8 / 2;
constexpr size_t OFF_WOH  = OFF_WHL + 64 * 40 * 64 * 8 / 2;  // 64*32*64*8 shorts
constexpr size_t OFF_WOL  = OFF_WOH + 64 * 32 * 64 * 8 / 2;

typedef __attribute__((ext_vector_type(8))) short short8v;
typedef __attribute__((ext_vector_type(4))) float f32x4;

static __device__ inline short f2bf(float f) {               // RTN-even fp32->bf16
    unsigned u = __builtin_bit_cast(unsigned, f);
    u += 0x7fffu + ((u >> 16) & 1u);
    return (short)(u >> 16);
}
static __device__ inline float bf2f(short s) {
    return __builtin_bit_cast(float, ((unsigned)(unsigned short)s) << 16);
}

__global__ __launch_bounds__(256)
void init_kernel(float* __restrict__ ws, const float* __restrict__ omega,
                 const float* __restrict__ b_offset, const float* __restrict__ tau_mem,
                 const float* __restrict__ gain) {
    size_t tid = (size_t)blockIdx.x * blockDim.x + threadIdx.x;
    size_t stride = (size_t)gridDim.x * blockDim.x;
    for (size_t i = tid; i < ZERO_END; i += stride) ws[i] = 0.0f;
    if (tid < H) {
        float om  = fabsf(omega[tid]);
        float om2 = om * om;
        float bb  = om2 * 0.005f + fabsf(b_offset[tid]);
        float al  = expf(-1.0f / fabsf(tau_mem[tid]));
        float g   = gain[tid];
        ws[OFF_COEF + 0 * H + tid] = g * (1.0f - 2.0f * bb * DT);  // k1
        ws[OFF_COEF + 1 * H + tid] = g * DT;                       // k2
        ws[OFF_COEF + 2 * H + tid] = g * om2 * DT;                 // k3
        ws[OFF_COEF + 3 * H + tid] = al;                           // alpha
        ws[OFF_COEF + 4 * H + tid] = 1.0f - al;
    }
}

// W [N rows x Kd] fp32 -> bf16 hi/lo, MFMA B-fragment order:
// flat short8 idx g = (cg*nks + ks)*64 + lane; col=cg*16+(lane&15), k=ks*32+((lane>>4)<<3)
template <int NKS, int KD>
__global__ __launch_bounds__(256)
void convert_kernel(const float* __restrict__ W, short* __restrict__ WH,
                    short* __restrict__ WL) {
    int g = blockIdx.x * 256 + threadIdx.x;
    int lane = g & 63;
    int ks = (g >> 6) % NKS;
    int cg = g / (NKS * 64);
    int col = cg * 16 + (lane & 15);
    int k = ks * 32 + ((lane >> 4) << 3);
    const float* src = W + (size_t)col * KD + k;
    short8v hi, lo;
    #pragma unroll
    for (int j = 0; j < 8; ++j) {
        float v = src[j];
        short h = f2bf(v);
        hi[j] = h;
        lo[j] = f2bf(v - bf2f(h));
    }
    *(short8v*)(WH + (size_t)g * 8) = hi;
    *(short8v*)(WL + (size_t)g * 8) = lo;
}

// One timestep. Per WG: 32 rows x 16 cols. Shared-A dual GEMM:
//   q      = hu^s @ W_o^T           -> ou = al*ou + (1-al)*q ; osum += ou
//   in_sum = [x_s, hu^s] @ W_h^T    -> harmonic update -> hu^{s+1}   (!LAST)
// 8 waves = 2 mtiles x 4 kslices; 3-MFMA bf16 hi/lo fp32 emulation.
template <bool LAST>
__global__ __launch_bounds__(512)
void step_kernel(const float* __restrict__ xs,
                 const float* __restrict__ huf_cur, const short* __restrict__ huh_cur,
                 const short* __restrict__ hul_cur,
                 float* __restrict__ huf_nxt, short* __restrict__ huh_nxt,
                 short* __restrict__ hul_nxt, float* __restrict__ ws) {
    __shared__ float redS[4][32][18];
    __shared__ float redP[4][32][18];
    const float* coef = ws + OFF_COEF;
    float* hv   = ws + OFF_HV;
    float* ou   = ws + OFF_OU;
    float* osum = ws + OFF_OSUM;
    const short8v* WHH = (const short8v*)(ws + OFF_WHH);
    const short8v* WHL = (const short8v*)(ws + OFF_WHL);
    const short8v* WOH = (const short8v*)(ws + OFF_WOH);
    const short8v* WOL = (const short8v*)(ws + OFF_WOL);

    const int wg = blockIdx.x;
    const int xcd = wg & 7, idx = wg >> 3;       // 32 WGs per XCD
    const int colsub = idx & 7, rowt = idx >> 3; // 8 col-subs x 4 row-tiles
    const int col0 = xcd * 128 + colsub * 16;
    const int row0 = rowt * 32;
    const int colgrp = xcd * 8 + colsub;

    const int tid = threadIdx.x;
    const int wid = tid >> 6, lane = tid & 63;
    const int mtile = wid & 1, ksl = wid >> 1;   // 2 mtiles x 4 kslices
    const int rowg = row0 + mtile * 16 + (lane & 15);
    const int koff = (lane >> 4) << 3;

    const short* huh = huh_cur + (size_t)rowg * H + koff;
    const short* hul = hul_cur + (size_t)rowg * H + koff;
    const short8v* BOH = WOH + (size_t)colgrp * NKS_O * 64 + lane;
    const short8v* BOL = WOL + (size_t)colgrp * NKS_O * 64 + lane;
    const short8v* BHH = WHH + (size_t)colgrp * NKS_H * 64 + lane;
    const short8v* BHL = WHL + (size_t)colgrp * NKS_H * 64 + lane;

    f32x4 accS = {0, 0, 0, 0}, accP = {0, 0, 0, 0};

    // hu k-range: 8 ks per kslice, shared A for W_o and W_h(hu part)
    #pragma unroll 2
    for (int ks = ksl * 8; ks < ksl * 8 + 8; ++ks) {
        short8v ah = *(const short8v*)(huh + ks * 32);
        short8v al = *(const short8v*)(hul + ks * 32);
        short8v bh = BOH[ks * 64];
        short8v bl = BOL[ks * 64];
        accP = __builtin_amdgcn_mfma_f32_16x16x32_bf16(ah, bh, accP, 0, 0, 0);
        accP = __builtin_amdgcn_mfma_f32_16x16x32_bf16(al, bh, accP, 0, 0, 0);
        accP = __builtin_amdgcn_mfma_f32_16x16x32_bf16(ah, bl, accP, 0, 0, 0);
        if (!LAST) {
            short8v ch = BHH[(8 + ks) * 64];
            short8v cl = BHL[(8 + ks) * 64];
            accS = __builtin_amdgcn_mfma_f32_16x16x32_bf16(ah, ch, accS, 0, 0, 0);
            accS = __builtin_amdgcn_mfma_f32_16x16x32_bf16(al, ch, accS, 0, 0, 0);
            accS = __builtin_amdgcn_mfma_f32_16x16x32_bf16(ah, cl, accS, 0, 0, 0);
        }
    }
    // x part: 2 ks per kslice (in_sum only), split fp32 in-register
    if (!LAST) {
        const float* xrow = xs + (size_t)rowg * I + koff;
        #pragma unroll
        for (int ks = ksl * 2; ks < ksl * 2 + 2; ++ks) {
            float4 a0 = *(const float4*)(xrow + ks * 32);
            float4 a1 = *(const float4*)(xrow + ks * 32 + 4);
            float av[8] = {a0.x, a0.y, a0.z, a0.w, a1.x, a1.y, a1.z, a1.w};
            short8v ah, al;
            #pragma unroll
            for (int j = 0; j < 8; ++j) {
                short h = f2bf(av[j]);
                ah[j] = h;
                al[j] = f2bf(av[j] - bf2f(h));
            }
            short8v ch = BHH[ks * 64];
            short8v cl = BHL[ks * 64];
            accS = __builtin_amdgcn_mfma_f32_16x16x32_bf16(ah, ch, accS, 0, 0, 0);
            accS = __builtin_amdgcn_mfma_f32_16x16x32_bf16(al, ch, accS, 0, 0, 0);
            accS = __builtin_amdgcn_mfma_f32_16x16x32_bf16(ah, cl, accS, 0, 0, 0);
        }
    }

    // C/D layout: col = lane&15, row = (lane>>4)*4 + r   [HW-verified round 2]
    #pragma unroll
    for (int r = 0; r < 4; ++r) {
        int crow = mtile * 16 + ((lane >> 4) << 2) + r;
        redP[ksl][crow][lane & 15] = accP[r];
        if (!LAST) redS[ksl][crow][lane & 15] = accS[r];
    }
    __syncthreads();

    if (tid < 512) {
        int r = tid >> 4, c = tid & 15;
        float p = (redP[0][r][c] + redP[1][r][c]) + (redP[2][r][c] + redP[3][r][c]);
        int gcol = col0 + c, grow = row0 + r;
        size_t ix = (size_t)grow * H + gcol;
        float al  = coef[3 * H + gcol];
        float alm = coef[4 * H + gcol];
        float oun = ou[ix] * al + p * alm;
        ou[ix] = oun;
        osum[ix] += oun;
        if (!LAST) {
            float s = (redS[0][r][c] + redS[1][r][c]) + (redS[2][r][c] + redS[3][r][c]);
            float k1 = coef[gcol], k2 = coef[H + gcol], k3 = coef[2 * H + gcol];
            float huo = huf_cur[ix];
            float hvn = hv[ix] + huo * DT;
            float hun = k1 * huo + k2 * s - k3 * hvn;
            hv[ix] = hvn;
            huf_nxt[ix] = hun;
            short h = f2bf(hun);
            huh_nxt[ix] = h;
            hul_nxt[ix] = f2bf(hun - bf2f(h));
        }
    }
}

// out = osum @ W_out^T + T*b_out  (fp32 scalar, proven round 1)
__global__ __launch_bounds__(256)
void readout_kernel(const float* __restrict__ ou_sum, const float* __restrict__ W_out,
                    const float* __restrict__ b_out, float* __restrict__ out) {
    constexpr int KC = 128, BT = 32, CT = 16;
    __shared__ float act[BT][KC + 4];
    __shared__ float w[CT][KC + 4];
    int wg = blockIdx.x;
    int bt = wg & 3, cg = wg >> 2;
    int row0 = bt * BT, col0 = cg * CT;
    int tid = threadIdx.x;
    int c = tid & 15, rr = tid >> 4;

    float4 acc0 = {0, 0, 0, 0}, acc1 = {0, 0, 0, 0};
    for (int kc = 0; kc < H / KC; ++kc) {
        int k0 = kc * KC;
        for (int i = tid; i < BT * (KC / 4); i += 256) {
            int r = i >> 5, c4 = (i & 31) * 4;
            *(float4*)&act[r][c4] = *(const float4*)&ou_sum[(size_t)(row0 + r) * H + k0 + c4];
        }
        for (int i = tid; i < CT * (KC / 4); i += 256) {
            int r = i >> 5, c4 = (i & 31) * 4;
            *(float4*)&w[r][c4] = *(const float4*)&W_out[(size_t)(col0 + r) * H + k0 + c4];
        }
        __syncthreads();
        #pragma unroll
        for (int k4 = 0; k4 < KC / 4; ++k4) {
            float4 a0 = *(const float4*)&act[rr][k4 * 4];
            float4 a1 = *(const float4*)&act[rr + 16][k4 * 4];
            float4 w0 = *(const float4*)&w[c][k4 * 4];
            acc0.x = fmaf(a0.x, w0.x, acc0.x); acc0.y = fmaf(a0.y, w0.y, acc0.y);
            acc0.z = fmaf(a0.z, w0.z, acc0.z); acc0.w = fmaf(a0.w, w0.w, acc0.w);
            acc1.x = fmaf(a1.x, w0.x, acc1.x); acc1.y = fmaf(a1.y, w0.y, acc1.y);
            acc1.z = fmaf(a1.z, w0.z, acc1.z); acc1.w = fmaf(a1.w, w0.w, acc1.w);
        }
        __syncthreads();
    }
    float v0 = (acc0.x + acc0.y) + (acc0.z + acc0.w);
    float v1 = (acc1.x + acc1.y) + (acc1.z + acc1.w);
    int gcol = col0 + c;
    float bo = b_out[gcol] * (float)T;
    out[(size_t)(row0 + rr) * O + gcol] = v0 + bo;
    out[(size_t)(row0 + rr + 16) * O + gcol] = v1 + bo;
}

extern "C" void kernel_launch(void* const* d_in, const int* in_sizes, int n_in,
                              void* d_out, int out_size, void* d_ws, size_t ws_size,
                              hipStream_t stream) {
    const float* x        = (const float*)d_in[0];
    const float* W_h      = (const float*)d_in[1];
    const float* gain     = (const float*)d_in[2];
    const float* omega    = (const float*)d_in[3];
    const float* b_offset = (const float*)d_in[4];
    const float* W_o      = (const float*)d_in[5];
    const float* tau_mem  = (const float*)d_in[6];
    const float* W_out    = (const float*)d_in[7];
    const float* b_out    = (const float*)d_in[8];
    float* ws  = (float*)d_ws;
    float* out = (float*)d_out;

    init_kernel<<<512, 256, 0, stream>>>(ws, omega, b_offset, tau_mem, gain);
    convert_kernel<64 * 40 / 64, K><<<640, 256, 0, stream>>>(  // NKS=40
        W_h, (short*)(ws + OFF_WHH), (short*)(ws + OFF_WHL));
    convert_kernel<64 * 32 / 64, H><<<512, 256, 0, stream>>>(  // NKS=32
        W_o, (short*)(ws + OFF_WOH), (short*)(ws + OFF_WOL));

    float* huf[2] = {ws + OFF_HUF0, ws + OFF_HUF1};
    short* huh[2] = {(short*)(ws + OFF_HUH0), (short*)(ws + OFF_HUH1)};
    short* hul[2] = {(short*)(ws + OFF_HUL0), (short*)(ws + OFF_HUL1)};

    for (int s = 0; s < T; ++s) {
        int a = s & 1, b = (s + 1) & 1;
        step_kernel<false><<<256, 512, 0, stream>>>(
            x + (size_t)s * B * I, huf[a], huh[a], hul[a],
            huf[b], huh[b], hul[b], ws);
    }
    // final LI update with hu^T (T even -> buffer 0)
    step_kernel<true><<<256, 512, 0, stream>>>(
        nullptr, huf[0], huh[0], hul[0], nullptr, nullptr, nullptr, ws);

    readout_kernel<<<64, 256, 0, stream>>>(ws + OFF_OSUM, W_out, b_out, out);
}